// Round 7
// baseline (23.923 us; speedup 1.0000x reference)
//
#include <hip/hip_runtime.h>

#define NPATCH 196
#define BATCH  8192
#define NPAIR  (BATCH * NPATCH / 2)   // patch pairs (2 adjacent patches each)
#define HALF   (NPAIR / 2)            // threads; each handles pairs 2u, 2u+1

typedef float f4 __attribute__((ext_vector_type(4)));

// Analytic solution of the 4-qubit circuit (Heisenberg picture):
//   z0 = cos(p0) cos(t0)
//   z1 = cos(p0) cos(t0) cos(t1+p1)
//   z2 = z1 * [cos(p4) cos(t2) + sin(p4) sin(p2) sin(t2) sin(t3+p3)]
//   z3 = cos(t2) cos(t3+p3)
// (t0..t3) = (TL, TR, BL, BR) pixels of the 2x2 patch. Exact.
__global__ __launch_bounds__(256) void quanv_kernel(
    const float* __restrict__ x,   // [B, 784]
    const float* __restrict__ rp,  // [5]
    f4* __restrict__ out)          // [B*196] f4 = [B, 784]
{
    int u = blockIdx.x * 256 + threadIdx.x;
    if (u >= HALF) return;

    // pair index -> load base: 98 pairs/image, 7 pairs per patch-row
    auto base_of = [](int n2) {
        int b   = n2 / 98;
        int r   = n2 - b * 98;
        int pi  = r / 7;
        int pjp = r - pi * 7;
        return b * 784 + pi * 56 + pjp * 4;   // 16B-aligned
    };

    // two ADJACENT pair-units: wave footprint = one contiguous input span
    int ba = base_of(2 * u);
    int bb = base_of(2 * u + 1);

    // Issue all 4 independent 16B loads before any compute (MLP).
    f4 topA = *(const f4*)(x + ba);
    f4 botA = *(const f4*)(x + ba + 28);
    f4 topB = *(const f4*)(x + bb);
    f4 botB = *(const f4*)(x + bb + 28);

    // uniform circuit constants
    float p1 = rp[1], p3 = rp[3];
    float K0  = __cosf(rp[0]);
    float K4  = __cosf(rp[4]);
    float K24 = __sinf(rp[4]) * __sinf(rp[2]);

    #define PATCH(T0, T1, B0, B1, O) {                      \
        float ct0 = __cosf(T0);                             \
        float c1  = __cosf((T1) + p1);                      \
        float st2, ct2; __sincosf((B0), &st2, &ct2);        \
        float s3, c3;   __sincosf((B1) + p3, &s3, &c3);     \
        float z0 = K0 * ct0;                                \
        float z1 = z0 * c1;                                 \
        float z2 = z1 * (K4 * ct2 + K24 * st2 * s3);        \
        float z3 = ct2 * c3;                                \
        O = (f4){z0, z1, z2, z3}; }

    f4 o0, o1, o2, o3;
    PATCH(topA.x, topA.y, botA.x, botA.y, o0)
    PATCH(topA.z, topA.w, botA.z, botA.w, o1)
    PATCH(topB.x, topB.y, botB.x, botB.y, o2)
    PATCH(topB.z, topB.w, botB.z, botB.w, o3)
    #undef PATCH

    // write-once output: non-temporal stores, 64B contiguous per thread
    size_t ob = (size_t)4 * u;
    __builtin_nontemporal_store(o0, out + ob);
    __builtin_nontemporal_store(o1, out + ob + 1);
    __builtin_nontemporal_store(o2, out + ob + 2);
    __builtin_nontemporal_store(o3, out + ob + 3);
}

extern "C" void kernel_launch(void* const* d_in, const int* in_sizes, int n_in,
                              void* d_out, int out_size, void* d_ws, size_t ws_size,
                              hipStream_t stream) {
    const float* x  = (const float*)d_in[0];
    const float* rp = (const float*)d_in[1];
    f4* out = (f4*)d_out;
    int blocks = (HALF + 255) / 256;   // 1568, exact divide
    quanv_kernel<<<blocks, 256, 0, stream>>>(x, rp, out);
}

// Round 8
// 18.007 us; speedup vs baseline: 1.3285x; 1.3285x over previous
//
#include <hip/hip_runtime.h>

#define NPATCH 196
#define BATCH  8192
#define NPAIR  (BATCH * NPATCH / 2)   // patch pairs (2 adjacent patches each)
#define NTHR   (NPAIR / 4)            // each thread handles 4 pair-units

typedef float f4 __attribute__((ext_vector_type(4)));

// Analytic solution of the 4-qubit circuit (Heisenberg picture):
//   z0 = cos(p0) cos(t0)
//   z1 = cos(p0) cos(t0) cos(t1+p1)
//   z2 = z1 * [cos(p4) cos(t2) + sin(p4) sin(p2) sin(t2) sin(t3+p3)]
//   z3 = cos(t2) cos(t3+p3)
// (t0..t3) = (TL, TR, BL, BR) pixels of the 2x2 patch. Exact.
//
// Wave-strided unit assignment: wave W (one per 64-thread block) owns the
// contiguous superblock of 256 pair-units [W*256, W*256+256); lane l takes
// units W*256 + k*64 + l, k=0..3. Every load/store instruction is
// lane-contiguous (consecutive lanes -> consecutive 16B chunks), and each
// wave touches only 2 contiguous input spans + 1 contiguous output span.
__global__ __launch_bounds__(64) void quanv_kernel(
    const float* __restrict__ x,   // [B, 784]
    const float* __restrict__ rp,  // [5]
    f4* __restrict__ out)          // [B*196] f4 = [B, 784]
{
    int W = blockIdx.x;            // wave id (block == 1 wave)
    int l = threadIdx.x;           // lane

    int u0 = W * 256 + l;          // + 0*64
    int u1 = u0 + 64;
    int u2 = u0 + 128;
    int u3 = u0 + 192;

    // pair index -> load base: 98 pairs/image, 7 pairs per patch-row
    auto base_of = [](int n2) {
        int b   = n2 / 98;
        int r   = n2 - b * 98;
        int pi  = r / 7;
        int pjp = r - pi * 7;
        return b * 784 + pi * 56 + pjp * 4;   // 16B-aligned
    };

    int b0 = base_of(u0);
    int b1 = base_of(u1);
    int b2 = base_of(u2);
    int b3 = base_of(u3);

    // Issue all 8 independent 16B loads before any compute (max MLP).
    f4 top0 = *(const f4*)(x + b0);
    f4 bot0 = *(const f4*)(x + b0 + 28);
    f4 top1 = *(const f4*)(x + b1);
    f4 bot1 = *(const f4*)(x + b1 + 28);
    f4 top2 = *(const f4*)(x + b2);
    f4 bot2 = *(const f4*)(x + b2 + 28);
    f4 top3 = *(const f4*)(x + b3);
    f4 bot3 = *(const f4*)(x + b3 + 28);

    // uniform circuit constants
    float p1 = rp[1], p3 = rp[3];
    float K0  = __cosf(rp[0]);
    float K4  = __cosf(rp[4]);
    float K24 = __sinf(rp[4]) * __sinf(rp[2]);

    #define PATCH(T0, T1, B0, B1, O) {                      \
        float ct0 = __cosf(T0);                             \
        float c1  = __cosf((T1) + p1);                      \
        float st2, ct2; __sincosf((B0), &st2, &ct2);        \
        float s3, c3;   __sincosf((B1) + p3, &s3, &c3);     \
        float z0 = K0 * ct0;                                \
        float z1 = z0 * c1;                                 \
        float z2 = z1 * (K4 * ct2 + K24 * st2 * s3);        \
        float z3 = ct2 * c3;                                \
        O = (f4){z0, z1, z2, z3}; }

    f4 oA, oB;
    #define DO_UNIT(TOP, BOT, IDX) {                                 \
        PATCH(TOP.x, TOP.y, BOT.x, BOT.y, oA)                        \
        PATCH(TOP.z, TOP.w, BOT.z, BOT.w, oB)                        \
        __builtin_nontemporal_store(oA, out + (size_t)2 * (IDX));    \
        __builtin_nontemporal_store(oB, out + (size_t)2 * (IDX) + 1); }

    DO_UNIT(top0, bot0, u0)
    DO_UNIT(top1, bot1, u1)
    DO_UNIT(top2, bot2, u2)
    DO_UNIT(top3, bot3, u3)

    #undef DO_UNIT
    #undef PATCH
}

extern "C" void kernel_launch(void* const* d_in, const int* in_sizes, int n_in,
                              void* d_out, int out_size, void* d_ws, size_t ws_size,
                              hipStream_t stream) {
    const float* x  = (const float*)d_in[0];
    const float* rp = (const float*)d_in[1];
    f4* out = (f4*)d_out;
    int blocks = NTHR / 64;   // 3136 one-wave blocks, exact divide
    quanv_kernel<<<blocks, 64, 0, stream>>>(x, rp, out);
}

// Round 9
// 11.067 us; speedup vs baseline: 2.1616x; 1.6271x over previous
//
#include <hip/hip_runtime.h>

typedef float f4 __attribute__((ext_vector_type(4)));

#define TOTAL_F4   (8192 * 196)   // output f4s == input f4s (both 6.4MB*4)
#define BLK_THR    448            // 7 waves per block
#define NBLOCKS    (TOTAL_F4 / BLK_THR)   // 3584, exact

// Analytic solution of the 4-qubit circuit (Heisenberg picture):
//   z0 = cos(p0) cos(t0)
//   z1 = cos(p0) cos(t0) cos(t1+p1)
//   z2 = z1 * [cos(p4) cos(t2) + sin(p4) sin(p2) sin(t2) sin(t3+p3)]
//   z3 = cos(t2) cos(t3+p3)
// (t0,t1,t2,t3) = (TL, TR, BL, BR) pixels of the 2x2 patch. Exact.
//
// Block-level layout trick: 448 consecutive input f4s = 1792 floats =
// 64 whole image rows = 32 row-pairs (rows never straddle: 784%28==0,
// 1792%28==0). Those 32 row-pairs contain exactly 448 patches, and their
// output f4 indices are the SAME 448 consecutive slots:
//   out_idx = q_global*14 + pj = 448*blk + (14*q_local + pj) = 448*blk + tid.
// So: stage 7168B contiguous -> LDS, compute 1 patch/thread from 4 floats,
// store 7168B contiguous. Both global streams are perfectly coalesced and
// 64B-line-exact.
__global__ __launch_bounds__(BLK_THR) void quanv_kernel(
    const float* __restrict__ x,   // [B*784]
    const float* __restrict__ rp,  // [5]
    f4* __restrict__ out)          // [B*196] f4
{
    __shared__ float lds[BLK_THR * 4];   // 7168 B
    int t = threadIdx.x;
    size_t gbase = (size_t)blockIdx.x * BLK_THR;

    // stage: perfectly contiguous 16B/lane
    ((f4*)lds)[t] = ((const f4*)x)[gbase + t];
    __syncthreads();

    // thread -> (local row-pair q, patch col pj)
    int q  = t / 14;
    int pj = t - q * 14;
    int o  = 56 * q + 2 * pj;       // float offset of TL pixel in LDS
    float t0 = lds[o],      t1 = lds[o + 1];
    float t2 = lds[o + 28], t3 = lds[o + 29];

    // uniform circuit constants
    float p1 = rp[1], p3 = rp[3];
    float K0  = __cosf(rp[0]);
    float K4  = __cosf(rp[4]);
    float K24 = __sinf(rp[4]) * __sinf(rp[2]);

    float ct0 = __cosf(t0);
    float c1  = __cosf(t1 + p1);
    float st2, ct2; __sincosf(t2, &st2, &ct2);
    float s3, c3;   __sincosf(t3 + p3, &s3, &c3);
    float z0 = K0 * ct0;
    float z1 = z0 * c1;
    float z2 = z1 * (K4 * ct2 + K24 * st2 * s3);
    float z3 = ct2 * c3;

    __builtin_nontemporal_store((f4){z0, z1, z2, z3}, out + gbase + t);
}

extern "C" void kernel_launch(void* const* d_in, const int* in_sizes, int n_in,
                              void* d_out, int out_size, void* d_ws, size_t ws_size,
                              hipStream_t stream) {
    const float* x  = (const float*)d_in[0];
    const float* rp = (const float*)d_in[1];
    f4* out = (f4*)d_out;
    quanv_kernel<<<NBLOCKS, BLK_THR, 0, stream>>>(x, rp, out);
}